// Round 1
// baseline (165.146 us; speedup 1.0000x reference)
//
#include <hip/hip_runtime.h>
#include <hip/hip_bf16.h>

// CorrelatorK3: B=8, N=256, D=64, F=64
// Stage 1: A[p,f] = (rbf0[p]·Q0w[f]+Q0b[f]) * (rbfd[p]·Qw[f]+Qb[f])   (bf16)
//          Bm[p,f] = (rbf0[p]·R0w[f]+R0b[f]) * (rbfd[p]·Rw[f]+Rb[f])  (bf16)
// Stage 2: C[b,n,j] = 0.02 * sum_{i,f} A[b,n,i,f] * Bm[b,i,j,f]

typedef __bf16 bf16x8 __attribute__((ext_vector_type(8)));
typedef float  f32x4  __attribute__((ext_vector_type(4)));
typedef int    i32x4  __attribute__((ext_vector_type(4)));

static __device__ __forceinline__ __bf16 f2bf(float x) {
  union { __hip_bfloat16 h; __bf16 b; } u;
  u.h = __float2bfloat16(x);
  return u.b;
}
static __device__ __forceinline__ unsigned short f2bfu(float x) {
  union { __hip_bfloat16 h; unsigned short s; } u;
  u.h = __float2bfloat16(x);
  return u.s;
}

// ---------------------------------------------------------------- stage 1 ---
__global__ __launch_bounds__(256, 1) void k_phase1(
    const float* __restrict__ rbf0, const float* __restrict__ rbfd,
    const float* __restrict__ Q0w, const float* __restrict__ Q0b,
    const float* __restrict__ Qw,  const float* __restrict__ Qb,
    const float* __restrict__ R0w, const float* __restrict__ R0b,
    const float* __restrict__ Rw,  const float* __restrict__ Rb,
    unsigned short* __restrict__ Aout, unsigned short* __restrict__ Bout)
{
  const int lane = threadIdx.x & 63;
  const int wave = threadIdx.x >> 6;
  const int fr   = lane & 15;   // MFMA row/col-in-tile
  const int kg   = lane >> 4;   // k-group (0..3)

  const float* Ws[4] = {Q0w, Qw, R0w, Rw};
  const float* Bs[4] = {Q0b, Qb, R0b, Rb};

  // Weight B-frags held in registers for the whole kernel.
  // B-frag (K=32 x N=16): lane holds W[ft*16 + (lane&15)][kt*32 + (lane>>4)*8 + j]
  bf16x8 wf[4][2][4];
  float  bini[4][4];
#pragma unroll
  for (int m = 0; m < 4; ++m) {
#pragma unroll
    for (int kt = 0; kt < 2; ++kt)
#pragma unroll
      for (int ft = 0; ft < 4; ++ft) {
        const float* p = Ws[m] + (ft * 16 + fr) * 64 + kt * 32 + kg * 8;
        f32x4 lo = *(const f32x4*)p;
        f32x4 hi = *(const f32x4*)(p + 4);
        bf16x8 w;
#pragma unroll
        for (int j = 0; j < 4; ++j) { w[j] = f2bf(lo[j]); w[j + 4] = f2bf(hi[j]); }
        wf[m][kt][ft] = w;
      }
#pragma unroll
    for (int ft = 0; ft < 4; ++ft) bini[m][ft] = Bs[m][ft * 16 + fr];
  }

  const int stride = gridDim.x * 4;
  // 32768 wave-tiles of 16 positions each
  for (int t = blockIdx.x * 4 + wave; t < 32768; t += stride) {
    const float* x0 = rbf0 + (size_t)t * 1024 + fr * 64 + kg * 8;
    const float* xd = rbfd + (size_t)t * 1024 + fr * 64 + kg * 8;
    f32x4 q0 = *(const f32x4*)(x0);
    f32x4 q1 = *(const f32x4*)(x0 + 4);
    f32x4 q2 = *(const f32x4*)(x0 + 32);
    f32x4 q3 = *(const f32x4*)(x0 + 36);
    f32x4 e0 = *(const f32x4*)(xd);
    f32x4 e1 = *(const f32x4*)(xd + 4);
    f32x4 e2 = *(const f32x4*)(xd + 32);
    f32x4 e3 = *(const f32x4*)(xd + 36);

    bf16x8 a0[2], ad[2];
#pragma unroll
    for (int j = 0; j < 4; ++j) {
      a0[0][j] = f2bf(q0[j]); a0[0][j + 4] = f2bf(q1[j]);
      a0[1][j] = f2bf(q2[j]); a0[1][j + 4] = f2bf(q3[j]);
      ad[0][j] = f2bf(e0[j]); ad[0][j + 4] = f2bf(e1[j]);
      ad[1][j] = f2bf(e2[j]); ad[1][j + 4] = f2bf(e3[j]);
    }

    f32x4 acc[4][4];
#pragma unroll
    for (int m = 0; m < 4; ++m)
#pragma unroll
      for (int ft = 0; ft < 4; ++ft) {
        float bv = bini[m][ft];
        acc[m][ft][0] = bv; acc[m][ft][1] = bv; acc[m][ft][2] = bv; acc[m][ft][3] = bv;
      }

#pragma unroll
    for (int kt = 0; kt < 2; ++kt)
#pragma unroll
      for (int ft = 0; ft < 4; ++ft) {
        acc[0][ft] = __builtin_amdgcn_mfma_f32_16x16x32_bf16(a0[kt], wf[0][kt][ft], acc[0][ft], 0, 0, 0);
        acc[1][ft] = __builtin_amdgcn_mfma_f32_16x16x32_bf16(ad[kt], wf[1][kt][ft], acc[1][ft], 0, 0, 0);
        acc[2][ft] = __builtin_amdgcn_mfma_f32_16x16x32_bf16(a0[kt], wf[2][kt][ft], acc[2][ft], 0, 0, 0);
        acc[3][ft] = __builtin_amdgcn_mfma_f32_16x16x32_bf16(ad[kt], wf[3][kt][ft], acc[3][ft], 0, 0, 0);
      }

    // C/D layout: col = lane&15 (f), row = (lane>>4)*4 + reg (position)
    const size_t base = (size_t)t * 1024;
#pragma unroll
    for (int ft = 0; ft < 4; ++ft)
#pragma unroll
      for (int r = 0; r < 4; ++r) {
        size_t off = base + (size_t)(kg * 4 + r) * 64 + ft * 16 + fr;
        Aout[off] = f2bfu(acc[0][ft][r] * acc[1][ft][r]);
        Bout[off] = f2bfu(acc[2][ft][r] * acc[3][ft][r]);
      }
  }
}

// ---------------------------------------------------------------- stage 2 ---
// Grid: 256 blocks = 8 b * 2 nt * 2 jt * 8 kc. Block = 4 waves (2x2), tile 128x128.
// K-chunk = 32 i-blocks (k = i*64 + f).
__global__ __launch_bounds__(256, 2) void k_phase2(
    const unsigned short* __restrict__ A, const unsigned short* __restrict__ Bm,
    float* __restrict__ C)
{
  __shared__ __align__(16) unsigned short Alds[128 * 64];
  __shared__ __align__(16) unsigned short Blds[128 * 64];

  const int tid  = threadIdx.x;
  const int lane = tid & 63;
  const int wave = tid >> 6;
  const int fr   = lane & 15;
  const int kg   = lane >> 4;

  const int bid = blockIdx.x;
  const int kc = bid & 7;
  const int jt = (bid >> 3) & 1;
  const int nt = (bid >> 4) & 1;
  const int b  = bid >> 5;
  const int n0 = nt * 128, j0 = jt * 128;
  const int wr = wave >> 1, wc = wave & 1;

  const unsigned short* Ab = A  + (size_t)b * 4194304;  // 256 * 16384
  const unsigned short* Bb = Bm + (size_t)b * 4194304;

  f32x4 acc[4][4];
#pragma unroll
  for (int mt = 0; mt < 4; ++mt)
#pragma unroll
    for (int nn = 0; nn < 4; ++nn) {
      acc[mt][nn][0] = 0.f; acc[mt][nn][1] = 0.f; acc[mt][nn][2] = 0.f; acc[mt][nn][3] = 0.f;
    }

  for (int ii = 0; ii < 32; ++ii) {
    const int i = kc * 32 + ii;

    // global -> regs (A tile: rows n0..n0+127, k = i*64..+64; B tile: rows j0..j0+127)
    i32x4 va[4], vb[4];
#pragma unroll
    for (int rep = 0; rep < 4; ++rep) {
      int c = tid + rep * 256;           // 1024 16B-chunks: 128 rows x 8 chunks
      int row = c >> 3, ch = c & 7;
      va[rep] = *(const i32x4*)(Ab + (size_t)(n0 + row) * 16384 + (size_t)i * 64 + ch * 8);
      vb[rep] = *(const i32x4*)(Bb + (size_t)i * 16384 + (size_t)(j0 + row) * 64 + ch * 8);
    }
    __syncthreads();   // previous iter's LDS reads done
#pragma unroll
    for (int rep = 0; rep < 4; ++rep) {
      int c = tid + rep * 256;
      int row = c >> 3, ch = c & 7;
      int sw = ch ^ (row & 7);           // XOR swizzle: kill 128B-stride bank conflict
      *(i32x4*)&Alds[row * 64 + sw * 8] = va[rep];
      *(i32x4*)&Blds[row * 64 + sw * 8] = vb[rep];
    }
    __syncthreads();

#pragma unroll
    for (int ks = 0; ks < 2; ++ks) {
      bf16x8 af[4], bfv[4];
#pragma unroll
      for (int mt = 0; mt < 4; ++mt) {
        int row = wr * 64 + mt * 16 + fr;
        int sw = (ks * 4 + kg) ^ (row & 7);
        af[mt] = *(const bf16x8*)&Alds[row * 64 + sw * 8];
      }
#pragma unroll
      for (int nn = 0; nn < 4; ++nn) {
        int row = wc * 64 + nn * 16 + fr;
        int sw = (ks * 4 + kg) ^ (row & 7);
        bfv[nn] = *(const bf16x8*)&Blds[row * 64 + sw * 8];
      }
#pragma unroll
      for (int mt = 0; mt < 4; ++mt)
#pragma unroll
        for (int nn = 0; nn < 4; ++nn)
          acc[mt][nn] = __builtin_amdgcn_mfma_f32_16x16x32_bf16(af[mt], bfv[nn], acc[mt][nn], 0, 0, 0);
    }
  }

  float* Cb = C + ((size_t)b << 16);
#pragma unroll
  for (int mt = 0; mt < 4; ++mt)
#pragma unroll
    for (int nn = 0; nn < 4; ++nn)
#pragma unroll
      for (int r = 0; r < 4; ++r) {
        int n = n0 + wr * 64 + mt * 16 + kg * 4 + r;
        int j = j0 + wc * 64 + nn * 16 + fr;
        atomicAdd(&Cb[n * 256 + j], acc[mt][nn][r] * 0.02f);
      }
}

// ------------------------------------------------------------------ launch --
extern "C" void kernel_launch(void* const* d_in, const int* in_sizes, int n_in,
                              void* d_out, int out_size, void* d_ws, size_t ws_size,
                              hipStream_t stream)
{
  const float* rbf0 = (const float*)d_in[0];
  const float* rbfd = (const float*)d_in[1];
  const float* Q0w  = (const float*)d_in[2];
  const float* Q0b  = (const float*)d_in[3];
  const float* Qw   = (const float*)d_in[4];
  const float* Qb   = (const float*)d_in[5];
  const float* R0w  = (const float*)d_in[6];
  const float* R0b  = (const float*)d_in[7];
  const float* Rw   = (const float*)d_in[8];
  const float* Rb   = (const float*)d_in[9];
  float* out = (float*)d_out;

  // workspace: A (64 MiB bf16) + Bm (64 MiB bf16) = 128 MiB
  unsigned short* Abuf = (unsigned short*)d_ws;
  unsigned short* Bbuf = Abuf + (size_t)33554432;

  hipMemsetAsync(d_out, 0, (size_t)out_size * sizeof(float), stream);
  hipLaunchKernelGGL(k_phase1, dim3(512), dim3(256), 0, stream,
                     rbf0, rbfd, Q0w, Q0b, Qw, Qb, R0w, R0b, Rw, Rb, Abuf, Bbuf);
  hipLaunchKernelGGL(k_phase2, dim3(256), dim3(256), 0, stream, Abuf, Bbuf, out);
}